// Round 12
// baseline (264.989 us; speedup 1.0000x reference)
//
#include <hip/hip_runtime.h>

#define DD 128

typedef __attribute__((ext_vector_type(8))) short short8;
typedef __attribute__((ext_vector_type(4))) float float4v;

static __device__ __forceinline__ unsigned short f2bf(float x) {
    unsigned u = __builtin_bit_cast(unsigned, x);
    u += 0x7fffu + ((u >> 16) & 1u);   // RNE
    return (unsigned short)(u >> 16);
}
static __device__ __forceinline__ float bflo(unsigned u) {
    return __builtin_bit_cast(float, u << 16);
}
static __device__ __forceinline__ float bfhi(unsigned u) {
    return __builtin_bit_cast(float, u & 0xffff0000u);
}

// ---- fused init: [0,128) emb@W1 bf16 table; [128,136) W2 swizzle; [136,185) zero cnt; [185] zero flags ----
__global__ __launch_bounds__(256) void k_init(const float* __restrict__ emb,
                                              const float* __restrict__ W1,
                                              const float* __restrict__ W2,
                                              unsigned* __restrict__ embW1b,
                                              unsigned short* __restrict__ Wb,
                                              int* __restrict__ cnt,
                                              int* __restrict__ bflag, int N, int B) {
    int blk = blockIdx.x;
    if (blk < 128) {
        int w = threadIdx.x >> 6;
        int t = threadIdx.x & 63;
        int p = blk * 4 + w;
        int c0 = t * 2, c1 = t * 2 + 1;
        float s0 = 0.f, s1 = 0.f;
#pragma unroll 8
        for (int k = 0; k < DD; k++) {
            float e = emb[p * DD + k];
            s0 += e * W1[k * DD + c0];
            s1 += e * W1[k * DD + c1];
        }
        embW1b[p * 64 + t] = (unsigned)f2bf(s0) | ((unsigned)f2bf(s1) << 16);
    } else if (blk < 136) {
        int t = (blk - 128) * 256 + threadIdx.x;   // 0..2047: (nt, ks, lane)
        int nt = t >> 8, ks = (t >> 6) & 3, lane = t & 63;
        int n = nt * 16 + (lane & 15);
        int kbase = ks * 32 + (lane >> 4) * 8;
        unsigned short* o = Wb + (size_t)t * 8;
#pragma unroll
        for (int j = 0; j < 8; j++)
            o[j] = f2bf(W2[(kbase + j) * DD + n]);
    } else if (blk < 136 + 49) {
        int base = (blk - 136) * 1024 + threadIdx.x * 4;
        if (base + 3 < N) {
            *(int4*)(cnt + base) = make_int4(0, 0, 0, 0);
        } else {
            if (base + 0 < N) cnt[base + 0] = 0;
            if (base + 1 < N) cnt[base + 1] = 0;
            if (base + 2 < N) cnt[base + 2] = 0;
        }
    } else {
        if ((int)threadIdx.x < B) bflag[threadIdx.x] = 0;
    }
}

// ---- in-degree histogram (int) ----
__global__ void k_hist(const int* __restrict__ dst, int* __restrict__ cnt, int E) {
    int e = blockIdx.x * blockDim.x + threadIdx.x;
    if (e < E) atomicAdd(&cnt[dst[e]], 1);
}

// ---- single-pass scan with decoupled lookback (B=49 blocks, all co-resident) ----
__global__ __launch_bounds__(256) void k_scan(const int* __restrict__ cnt,
                                              int* __restrict__ rowptr,
                                              int* __restrict__ cursor,
                                              float* __restrict__ dis,
                                              int* __restrict__ bpre,
                                              int* __restrict__ bflag, int N, int E) {
    __shared__ int sums[256];
    __shared__ int sTileBase;
    int t = threadIdx.x;
    int base = blockIdx.x * 1024 + t * 4;
    int c0 = 0, c1 = 0, c2 = 0, c3 = 0;
    if (base + 3 < N) {
        const int4 v = *(const int4*)(cnt + base);
        c0 = v.x; c1 = v.y; c2 = v.z; c3 = v.w;
    } else {
        if (base + 0 < N) c0 = cnt[base + 0];
        if (base + 1 < N) c1 = cnt[base + 1];
        if (base + 2 < N) c2 = cnt[base + 2];
        if (base + 3 < N) c3 = cnt[base + 3];
    }
    int ts = c0 + c1 + c2 + c3;
    sums[t] = ts;
    __syncthreads();
    for (int off = 1; off < 256; off <<= 1) {
        int v = (t >= off) ? sums[t - off] : 0;
        __syncthreads();
        sums[t] += v;
        __syncthreads();
    }
    int tileSum = sums[255];
    if (t == 0) {
        int pred = 0;
        if (blockIdx.x > 0) {
            while (__hip_atomic_load(&bflag[blockIdx.x - 1], __ATOMIC_ACQUIRE,
                                     __HIP_MEMORY_SCOPE_AGENT) == 0) {}
            pred = bpre[blockIdx.x - 1];
        }
        bpre[blockIdx.x] = pred + tileSum;
        __hip_atomic_store(&bflag[blockIdx.x], 1, __ATOMIC_RELEASE,
                           __HIP_MEMORY_SCOPE_AGENT);
        sTileBase = pred;
        if (blockIdx.x == 0) rowptr[N] = E;
    }
    __syncthreads();
    int pre = sTileBase + sums[t] - ts;
    if (base + 0 < N) { rowptr[base + 0] = pre;                cursor[base + 0] = pre;                dis[base + 0] = rsqrtf((float)c0 + 1.f); }
    if (base + 1 < N) { rowptr[base + 1] = pre + c0;           cursor[base + 1] = pre + c0;           dis[base + 1] = rsqrtf((float)c1 + 1.f); }
    if (base + 2 < N) { rowptr[base + 2] = pre + c0 + c1;      cursor[base + 2] = pre + c0 + c1;      dis[base + 2] = rsqrtf((float)c2 + 1.f); }
    if (base + 3 < N) { rowptr[base + 3] = pre + c0 + c1 + c2; cursor[base + 3] = pre + c0 + c1 + c2; dis[base + 3] = rsqrtf((float)c3 + 1.f); }
}

// ---- bucket edges by dst: ONE 4B packed record: src(16) | widx(9)<<16 | min(deg,127)<<25 ----
__global__ void k_bucket(const int* __restrict__ src, const int* __restrict__ dst,
                         const int* __restrict__ node_ids, const int* __restrict__ cnt,
                         int* __restrict__ cursor, unsigned* __restrict__ recs, int E) {
    int e = blockIdx.x * blockDim.x + threadIdx.x;
    if (e >= E) return;
    int s = src[e], d = dst[e];
    int dg = cnt[s]; if (dg > 127) dg = 127;
    unsigned rec = (unsigned)s | ((unsigned)node_ids[s] << 16) | ((unsigned)dg << 25);
    int pos = atomicAdd(&cursor[d], 1);
    recs[pos] = rec;
}

// ---- layer 1: 4 nodes/wave, lane-cooperative masked batches of 16 edges ----
__global__ __launch_bounds__(256) void k_node1(const int* __restrict__ rowptr,
                                               const unsigned* __restrict__ recs,
                                               const int* __restrict__ node_ids,
                                               const float* __restrict__ emb,
                                               const unsigned* __restrict__ embW1b,
                                               const float* __restrict__ dis,
                                               const float* __restrict__ b1,
                                               const float* __restrict__ g1,
                                               const float* __restrict__ beta1,
                                               unsigned* __restrict__ x1b, int N) {
    int gid = blockIdx.x * blockDim.x + threadIdx.x;
    int wave = gid >> 6;
    int lane = threadIdx.x & 63;
    int qtr = lane >> 4;
    int l = lane & 15;
    int qbase = lane & 48;
    int i = wave * 4 + qtr;
    if (i >= N) return;
    int r0 = rowptr[i], r1 = rowptr[i + 1];
    int c = l * 8;
    float a0 = 0.f, a1 = 0.f, a2 = 0.f, a3 = 0.f, a4 = 0.f, a5 = 0.f, a6 = 0.f, a7 = 0.f;
    for (int j0 = r0; j0 < r1; j0 += 16) {
        int pidx = j0 + l;
        unsigned rv = recs[(pidx < r1) ? pidx : (r1 - 1)];
        int lim = r1 - j0;
#pragma unroll
        for (int q = 0; q < 16; q++) {
            unsigned rec = __shfl(rv, qbase + q, 64);       // own-quarter lanes only
            float n = rsqrtf((float)(rec >> 25) + 1.0f);
            n = (q < lim) ? n : 0.f;
            uint4 a = *(const uint4*)(embW1b + ((rec >> 16) & 511u) * 64 + l * 4);
            a0 += bflo(a.x) * n; a1 += bfhi(a.x) * n;
            a2 += bflo(a.y) * n; a3 += bfhi(a.y) * n;
            a4 += bflo(a.z) * n; a5 += bfhi(a.z) * n;
            a6 += bflo(a.w) * n; a7 += bfhi(a.w) * n;
        }
    }
    float di = dis[i];
    int pid = node_ids[i];
    float4 ev0 = *(const float4*)(emb + (size_t)pid * DD + c);
    float4 ev1 = *(const float4*)(emb + (size_t)pid * DD + c + 4);
    uint4 hw = *(const uint4*)(embW1b + pid * 64 + l * 4);
    float4 bb0 = *(const float4*)(b1 + c);
    float4 bb1 = *(const float4*)(b1 + c + 4);
    float v0 = ev0.x + di * (a0 + di * bflo(hw.x)) + bb0.x;
    float v1 = ev0.y + di * (a1 + di * bfhi(hw.x)) + bb0.y;
    float v2 = ev0.z + di * (a2 + di * bflo(hw.y)) + bb0.z;
    float v3 = ev0.w + di * (a3 + di * bfhi(hw.y)) + bb0.w;
    float v4 = ev1.x + di * (a4 + di * bflo(hw.z)) + bb1.x;
    float v5 = ev1.y + di * (a5 + di * bfhi(hw.z)) + bb1.y;
    float v6 = ev1.z + di * (a6 + di * bflo(hw.w)) + bb1.z;
    float v7 = ev1.w + di * (a7 + di * bfhi(hw.w)) + bb1.w;
    float sum = v0 + v1 + v2 + v3 + v4 + v5 + v6 + v7;
#pragma unroll
    for (int o = 8; o >= 1; o >>= 1) sum += __shfl_xor(sum, o, 64);
    float mu = sum * (1.f / DD);
    float d0 = v0 - mu, d1 = v1 - mu, d2 = v2 - mu, d3 = v3 - mu;
    float d4 = v4 - mu, d5 = v5 - mu, d6 = v6 - mu, d7 = v7 - mu;
    float ss = d0 * d0 + d1 * d1 + d2 * d2 + d3 * d3 + d4 * d4 + d5 * d5 + d6 * d6 + d7 * d7;
#pragma unroll
    for (int o = 8; o >= 1; o >>= 1) ss += __shfl_xor(ss, o, 64);
    float r = rsqrtf(ss * (1.f / DD) + 1e-5f);
    float4 gg0 = *(const float4*)(g1 + c);
    float4 gg1 = *(const float4*)(g1 + c + 4);
    float4 be0 = *(const float4*)(beta1 + c);
    float4 be1 = *(const float4*)(beta1 + c + 4);
    float o0 = d0 * r * gg0.x + be0.x;
    float o1 = d1 * r * gg0.y + be0.y;
    float o2 = d2 * r * gg0.z + be0.z;
    float o3 = d3 * r * gg0.w + be0.w;
    float o4 = d4 * r * gg1.x + be1.x;
    float o5 = d5 * r * gg1.y + be1.y;
    float o6 = d6 * r * gg1.z + be1.z;
    float o7 = d7 * r * gg1.w + be1.w;
    uint4 pk;
    pk.x = (unsigned)f2bf(o0) | ((unsigned)f2bf(o1) << 16);
    pk.y = (unsigned)f2bf(o2) | ((unsigned)f2bf(o3) << 16);
    pk.z = (unsigned)f2bf(o4) | ((unsigned)f2bf(o5) << 16);
    pk.w = (unsigned)f2bf(o6) | ((unsigned)f2bf(o7) << 16);
    *(uint4*)(x1b + (size_t)i * 64 + l * 4) = pk;
}

// ---- h2b = bf16( (x1 @ W2) * dis[row] )  via bf16 MFMA; one wave per 16-row strip ----
__global__ __launch_bounds__(256) void k_gemm_mfma(const unsigned short* __restrict__ x1b,
                                                   const unsigned short* __restrict__ Wb,
                                                   const float* __restrict__ dis,
                                                   unsigned short* __restrict__ hb, int N) {
    int wave = (blockIdx.x * blockDim.x + threadIdx.x) >> 6;
    int lane = threadIdx.x & 63;
    int row0 = wave * 16;
    if (row0 >= N) return;
    int m = lane & 15, quad = lane >> 4;

    short8 afr[4];
    const short8* ap = (const short8*)(x1b + (size_t)(row0 + m) * DD + quad * 8);
#pragma unroll
    for (int ks = 0; ks < 4; ks++) afr[ks] = ap[ks * 4];

    float4 dv = *(const float4*)(dis + row0 + quad * 4);
    float dr[4] = {dv.x, dv.y, dv.z, dv.w};

    const short8* bp = (const short8*)Wb + (size_t)lane;
#pragma unroll
    for (int nt = 0; nt < 8; nt++) {
        float4v acc = {0.f, 0.f, 0.f, 0.f};
#pragma unroll
        for (int ks = 0; ks < 4; ks++) {
            short8 bfr = bp[(nt * 4 + ks) * 64];
            acc = __builtin_amdgcn_mfma_f32_16x16x32_bf16(afr[ks], bfr, acc, 0, 0, 0);
        }
        int col = nt * 16 + m;
#pragma unroll
        for (int r = 0; r < 4; r++) {
            int row = row0 + quad * 4 + r;
            if (row < N) hb[(size_t)row * DD + col] = f2bf(acc[r] * dr[r]);
        }
    }
}

// ---- layer 2: 4 nodes/wave, lane-cooperative masked batches of 16 edges ----
__global__ __launch_bounds__(256) void k_node2(const int* __restrict__ rowptr,
                                               const unsigned* __restrict__ recs,
                                               const unsigned* __restrict__ x1b,
                                               const unsigned* __restrict__ h2b,
                                               const float* __restrict__ dis,
                                               const float* __restrict__ b2,
                                               const float* __restrict__ g2,
                                               const float* __restrict__ beta2,
                                               float* __restrict__ out, int N) {
    int gid = blockIdx.x * blockDim.x + threadIdx.x;
    int wave = gid >> 6;
    int lane = threadIdx.x & 63;
    int qtr = lane >> 4;
    int l = lane & 15;
    int qbase = lane & 48;
    int i = wave * 4 + qtr;
    if (i >= N) return;
    int r0 = rowptr[i], r1 = rowptr[i + 1];
    int c = l * 8;
    float a0 = 0.f, a1 = 0.f, a2 = 0.f, a3 = 0.f, a4 = 0.f, a5 = 0.f, a6 = 0.f, a7 = 0.f;
    for (int j0 = r0; j0 < r1; j0 += 16) {
        int pidx = j0 + l;
        unsigned rv = recs[(pidx < r1) ? pidx : (r1 - 1)];
        int lim = r1 - j0;
#pragma unroll
        for (int q = 0; q < 16; q++) {
            unsigned s = __shfl(rv, qbase + q, 64) & 0xFFFFu;
            float w = (q < lim) ? 1.f : 0.f;
            uint4 a = *(const uint4*)(h2b + (size_t)s * 64 + l * 4);
            a0 += bflo(a.x) * w; a1 += bfhi(a.x) * w;
            a2 += bflo(a.y) * w; a3 += bfhi(a.y) * w;
            a4 += bflo(a.z) * w; a5 += bfhi(a.z) * w;
            a6 += bflo(a.w) * w; a7 += bfhi(a.w) * w;
        }
    }
    float di = dis[i];
    uint4 xv = *(const uint4*)(x1b + (size_t)i * 64 + l * 4);
    uint4 hv = *(const uint4*)(h2b + (size_t)i * 64 + l * 4);   // already scaled by dis[i]
    float4 bb0 = *(const float4*)(b2 + c);
    float4 bb1 = *(const float4*)(b2 + c + 4);
    float v0 = bflo(xv.x) + di * (a0 + bflo(hv.x)) + bb0.x;
    float v1 = bfhi(xv.x) + di * (a1 + bfhi(hv.x)) + bb0.y;
    float v2 = bflo(xv.y) + di * (a2 + bflo(hv.y)) + bb0.z;
    float v3 = bfhi(xv.y) + di * (a3 + bfhi(hv.y)) + bb0.w;
    float v4 = bflo(xv.z) + di * (a4 + bflo(hv.z)) + bb1.x;
    float v5 = bfhi(xv.z) + di * (a5 + bfhi(hv.z)) + bb1.y;
    float v6 = bflo(xv.w) + di * (a6 + bflo(hv.w)) + bb1.z;
    float v7 = bfhi(xv.w) + di * (a7 + bfhi(hv.w)) + bb1.w;
    float sum = v0 + v1 + v2 + v3 + v4 + v5 + v6 + v7;
#pragma unroll
    for (int o = 8; o >= 1; o >>= 1) sum += __shfl_xor(sum, o, 64);
    float mu = sum * (1.f / DD);
    float d0 = v0 - mu, d1 = v1 - mu, d2 = v2 - mu, d3 = v3 - mu;
    float d4 = v4 - mu, d5 = v5 - mu, d6 = v6 - mu, d7 = v7 - mu;
    float ss = d0 * d0 + d1 * d1 + d2 * d2 + d3 * d3 + d4 * d4 + d5 * d5 + d6 * d6 + d7 * d7;
#pragma unroll
    for (int o = 8; o >= 1; o >>= 1) ss += __shfl_xor(ss, o, 64);
    float r = rsqrtf(ss * (1.f / DD) + 1e-5f);
    float4 gg0 = *(const float4*)(g2 + c);
    float4 gg1 = *(const float4*)(g2 + c + 4);
    float4 be0 = *(const float4*)(beta2 + c);
    float4 be1 = *(const float4*)(beta2 + c + 4);
    float4 o0, o1;
    o0.x = d0 * r * gg0.x + be0.x;
    o0.y = d1 * r * gg0.y + be0.y;
    o0.z = d2 * r * gg0.z + be0.z;
    o0.w = d3 * r * gg0.w + be0.w;
    o1.x = d4 * r * gg1.x + be1.x;
    o1.y = d5 * r * gg1.y + be1.y;
    o1.z = d6 * r * gg1.z + be1.z;
    o1.w = d7 * r * gg1.w + be1.w;
    *(float4*)(out + (size_t)i * DD + c) = o0;
    *(float4*)(out + (size_t)i * DD + c + 4) = o1;
}

extern "C" void kernel_launch(void* const* d_in, const int* in_sizes, int n_in,
                              void* d_out, int out_size, void* d_ws, size_t ws_size,
                              hipStream_t stream) {
    const int* node_ids = (const int*)d_in[0];
    const int* edge_index = (const int*)d_in[1];
    const float* emb   = (const float*)d_in[2];
    const float* W1    = (const float*)d_in[3];
    const float* b1    = (const float*)d_in[4];
    const float* W2    = (const float*)d_in[5];
    const float* b2    = (const float*)d_in[6];
    const float* g1    = (const float*)d_in[7];
    const float* beta1 = (const float*)d_in[8];
    const float* g2    = (const float*)d_in[9];
    const float* beta2 = (const float*)d_in[10];
    const int N = in_sizes[0];
    const int E = in_sizes[1] / 2;
    const int* srcp = edge_index;
    const int* dstp = edge_index + E;
    float* out = (float*)d_out;

    char* base = (char*)d_ws;
    size_t off = 0;
    auto carve = [&](size_t bytes) -> void* {
        void* p = base + off;
        off += (bytes + 255) & ~(size_t)255;
        return p;
    };
    int*      cnt    = (int*)carve((size_t)N * 4);
    int*      rowptr = (int*)carve((size_t)(N + 1) * 4);
    int*      cursor = (int*)carve((size_t)N * 4);
    float*    dis    = (float*)carve((size_t)(N + 16) * 4);
    int*      bpre   = (int*)carve((size_t)256 * 4);
    int*      bflag  = (int*)carve((size_t)256 * 4);
    unsigned* recs   = (unsigned*)carve((size_t)E * 4);
    unsigned* embW1b = (unsigned*)carve((size_t)512 * 64 * 4);
    unsigned* x1b    = (unsigned*)carve((size_t)(N + 16) * 64 * 4);
    unsigned* h2b    = (unsigned*)carve((size_t)(N + 16) * 64 * 4);
    unsigned short* Wb = (unsigned short*)carve((size_t)DD * DD * 2);
    (void)ws_size; (void)n_in; (void)out_size;

    const int TB = 256;
    const int B = (N + 1023) / 1024;   // 49 scan tiles

    k_init<<<136 + B + 1, TB, 0, stream>>>(emb, W1, W2, embW1b, Wb, cnt, bflag, N, B);
    k_hist<<<(E + TB - 1) / TB, TB, 0, stream>>>(dstp, cnt, E);
    k_scan<<<B, 256, 0, stream>>>(cnt, rowptr, cursor, dis, bpre, bflag, N, E);
    k_bucket<<<(E + TB - 1) / TB, TB, 0, stream>>>(srcp, dstp, node_ids, cnt, cursor, recs, E);

    long long tn = (long long)((N + 3) / 4) * 64;   // one wave per 4 nodes
    int nodeBlocks = (int)((tn + TB - 1) / TB);
    k_node1<<<nodeBlocks, TB, 0, stream>>>(rowptr, recs, node_ids, emb, embW1b, dis,
                                           b1, g1, beta1, x1b, N);
    int waves = (N + 15) / 16;
    int gb = (waves + 3) / 4;
    k_gemm_mfma<<<gb, 256, 0, stream>>>((const unsigned short*)x1b, Wb, dis,
                                        (unsigned short*)h2b, N);
    k_node2<<<nodeBlocks, TB, 0, stream>>>(rowptr, recs, x1b, h2b, dis,
                                           b2, g2, beta2, out, N);
}

// Round 13
// 202.588 us; speedup vs baseline: 1.3080x; 1.3080x over previous
//
#include <hip/hip_runtime.h>

#define DD 128

typedef __attribute__((ext_vector_type(8))) short short8;
typedef __attribute__((ext_vector_type(4))) float float4v;

static __device__ __forceinline__ unsigned short f2bf(float x) {
    unsigned u = __builtin_bit_cast(unsigned, x);
    u += 0x7fffu + ((u >> 16) & 1u);   // RNE
    return (unsigned short)(u >> 16);
}
static __device__ __forceinline__ float bflo(unsigned u) {
    return __builtin_bit_cast(float, u << 16);
}
static __device__ __forceinline__ float bfhi(unsigned u) {
    return __builtin_bit_cast(float, u & 0xffff0000u);
}

// ---- fused init: [0,128) emb@W1 bf16 table; [128,136) W2 swizzle; [136,136+Z) zero cnt ----
__global__ __launch_bounds__(256) void k_init(const float* __restrict__ emb,
                                              const float* __restrict__ W1,
                                              const float* __restrict__ W2,
                                              unsigned* __restrict__ embW1b,
                                              unsigned short* __restrict__ Wb,
                                              int* __restrict__ cnt, int N) {
    int blk = blockIdx.x;
    if (blk < 128) {
        int w = threadIdx.x >> 6;
        int t = threadIdx.x & 63;
        int p = blk * 4 + w;
        int c0 = t * 2, c1 = t * 2 + 1;
        float s0 = 0.f, s1 = 0.f;
#pragma unroll 8
        for (int k = 0; k < DD; k++) {
            float e = emb[p * DD + k];
            s0 += e * W1[k * DD + c0];
            s1 += e * W1[k * DD + c1];
        }
        embW1b[p * 64 + t] = (unsigned)f2bf(s0) | ((unsigned)f2bf(s1) << 16);
    } else if (blk < 136) {
        int t = (blk - 128) * 256 + threadIdx.x;   // 0..2047: (nt, ks, lane)
        int nt = t >> 8, ks = (t >> 6) & 3, lane = t & 63;
        int n = nt * 16 + (lane & 15);
        int kbase = ks * 32 + (lane >> 4) * 8;
        unsigned short* o = Wb + (size_t)t * 8;
#pragma unroll
        for (int j = 0; j < 8; j++)
            o[j] = f2bf(W2[(kbase + j) * DD + n]);
    } else {
        int base = (blk - 136) * 1024 + threadIdx.x * 4;
        if (base + 3 < N) {
            *(int4*)(cnt + base) = make_int4(0, 0, 0, 0);
        } else {
            if (base + 0 < N) cnt[base + 0] = 0;
            if (base + 1 < N) cnt[base + 1] = 0;
            if (base + 2 < N) cnt[base + 2] = 0;
        }
    }
}

// ---- in-degree histogram (int) ----
__global__ void k_hist(const int* __restrict__ dst, int* __restrict__ cnt, int E) {
    int e = blockIdx.x * blockDim.x + threadIdx.x;
    if (e < E) atomicAdd(&cnt[dst[e]], 1);
}

// ---- scan phase 1: per-1024-tile exclusive prefix + block totals + dis ----
__global__ __launch_bounds__(256) void k_scan1(const int* __restrict__ cnt,
                                               int* __restrict__ rowptr,
                                               float* __restrict__ dis,
                                               int* __restrict__ bsum, int N) {
    __shared__ int sums[256];
    int t = threadIdx.x;
    int base = blockIdx.x * 1024 + t * 4;
    int c0 = 0, c1 = 0, c2 = 0, c3 = 0;
    if (base + 3 < N) {
        const int4 v = *(const int4*)(cnt + base);
        c0 = v.x; c1 = v.y; c2 = v.z; c3 = v.w;
    } else {
        if (base + 0 < N) c0 = cnt[base + 0];
        if (base + 1 < N) c1 = cnt[base + 1];
        if (base + 2 < N) c2 = cnt[base + 2];
        if (base + 3 < N) c3 = cnt[base + 3];
    }
    int ts = c0 + c1 + c2 + c3;
    sums[t] = ts;
    __syncthreads();
    for (int off = 1; off < 256; off <<= 1) {
        int v = (t >= off) ? sums[t - off] : 0;
        __syncthreads();
        sums[t] += v;
        __syncthreads();
    }
    int pre = sums[t] - ts;
    if (base + 0 < N) { rowptr[base + 0] = pre;                 dis[base + 0] = rsqrtf((float)c0 + 1.f); }
    if (base + 1 < N) { rowptr[base + 1] = pre + c0;            dis[base + 1] = rsqrtf((float)c1 + 1.f); }
    if (base + 2 < N) { rowptr[base + 2] = pre + c0 + c1;       dis[base + 2] = rsqrtf((float)c2 + 1.f); }
    if (base + 3 < N) { rowptr[base + 3] = pre + c0 + c1 + c2;  dis[base + 3] = rsqrtf((float)c3 + 1.f); }
    if (t == 255) bsum[blockIdx.x] = sums[255];
}

// ---- scan phase 2+3 fused: each block redundantly prefixes bsum (B<=256), applies offsets ----
__global__ __launch_bounds__(256) void k_scan23(int* __restrict__ rowptr,
                                                int* __restrict__ cursor,
                                                const int* __restrict__ bsum,
                                                int B, int N, int E) {
    __shared__ int pref[256];
    int t = threadIdx.x;
    pref[t] = (t < B) ? bsum[t] : 0;
    __syncthreads();
    int i = blockIdx.x * 256 + t;
    if (i < N) {
        int b = i >> 10;
        int off = 0;
        for (int k = 0; k < b; k++) off += pref[k];
        int v = rowptr[i] + off;
        rowptr[i] = v;
        cursor[i] = v;
    }
    if (i == 0) rowptr[N] = E;
}

// ---- bucket edges by dst: ONE 4B packed record: src(16) | widx(9)<<16 | min(deg,127)<<25 ----
__global__ void k_bucket(const int* __restrict__ src, const int* __restrict__ dst,
                         const int* __restrict__ node_ids, const int* __restrict__ cnt,
                         int* __restrict__ cursor, unsigned* __restrict__ recs, int E) {
    int e = blockIdx.x * blockDim.x + threadIdx.x;
    if (e >= E) return;
    int s = src[e], d = dst[e];
    int dg = cnt[s]; if (dg > 127) dg = 127;
    unsigned rec = (unsigned)s | ((unsigned)node_ids[s] << 16) | ((unsigned)dg << 25);
    int pos = atomicAdd(&cursor[d], 1);
    recs[pos] = rec;
}

// ---- layer 1: 4 nodes/wave, lane-cooperative masked batches of 16 edges ----
__global__ __launch_bounds__(256) void k_node1(const int* __restrict__ rowptr,
                                               const unsigned* __restrict__ recs,
                                               const int* __restrict__ node_ids,
                                               const float* __restrict__ emb,
                                               const unsigned* __restrict__ embW1b,
                                               const float* __restrict__ dis,
                                               const float* __restrict__ b1,
                                               const float* __restrict__ g1,
                                               const float* __restrict__ beta1,
                                               unsigned* __restrict__ x1b, int N) {
    int gid = blockIdx.x * blockDim.x + threadIdx.x;
    int wave = gid >> 6;
    int lane = threadIdx.x & 63;
    int qtr = lane >> 4;
    int l = lane & 15;
    int qbase = lane & 48;
    int i = wave * 4 + qtr;
    if (i >= N) return;
    int r0 = rowptr[i], r1 = rowptr[i + 1];
    int c = l * 8;
    float a0 = 0.f, a1 = 0.f, a2 = 0.f, a3 = 0.f, a4 = 0.f, a5 = 0.f, a6 = 0.f, a7 = 0.f;
    for (int j0 = r0; j0 < r1; j0 += 16) {
        int pidx = j0 + l;
        unsigned rv = recs[(pidx < r1) ? pidx : (r1 - 1)];
        int lim = r1 - j0;
#pragma unroll
        for (int q = 0; q < 16; q++) {
            unsigned rec = __shfl(rv, qbase + q, 64);       // own-quarter lanes only
            float n = rsqrtf((float)(rec >> 25) + 1.0f);
            n = (q < lim) ? n : 0.f;
            uint4 a = *(const uint4*)(embW1b + ((rec >> 16) & 511u) * 64 + l * 4);
            a0 += bflo(a.x) * n; a1 += bfhi(a.x) * n;
            a2 += bflo(a.y) * n; a3 += bfhi(a.y) * n;
            a4 += bflo(a.z) * n; a5 += bfhi(a.z) * n;
            a6 += bflo(a.w) * n; a7 += bfhi(a.w) * n;
        }
    }
    float di = dis[i];
    int pid = node_ids[i];
    float4 ev0 = *(const float4*)(emb + (size_t)pid * DD + c);
    float4 ev1 = *(const float4*)(emb + (size_t)pid * DD + c + 4);
    uint4 hw = *(const uint4*)(embW1b + pid * 64 + l * 4);
    float4 bb0 = *(const float4*)(b1 + c);
    float4 bb1 = *(const float4*)(b1 + c + 4);
    float v0 = ev0.x + di * (a0 + di * bflo(hw.x)) + bb0.x;
    float v1 = ev0.y + di * (a1 + di * bfhi(hw.x)) + bb0.y;
    float v2 = ev0.z + di * (a2 + di * bflo(hw.y)) + bb0.z;
    float v3 = ev0.w + di * (a3 + di * bfhi(hw.y)) + bb0.w;
    float v4 = ev1.x + di * (a4 + di * bflo(hw.z)) + bb1.x;
    float v5 = ev1.y + di * (a5 + di * bfhi(hw.z)) + bb1.y;
    float v6 = ev1.z + di * (a6 + di * bflo(hw.w)) + bb1.z;
    float v7 = ev1.w + di * (a7 + di * bfhi(hw.w)) + bb1.w;
    float sum = v0 + v1 + v2 + v3 + v4 + v5 + v6 + v7;
#pragma unroll
    for (int o = 8; o >= 1; o >>= 1) sum += __shfl_xor(sum, o, 64);
    float mu = sum * (1.f / DD);
    float d0 = v0 - mu, d1 = v1 - mu, d2 = v2 - mu, d3 = v3 - mu;
    float d4 = v4 - mu, d5 = v5 - mu, d6 = v6 - mu, d7 = v7 - mu;
    float ss = d0 * d0 + d1 * d1 + d2 * d2 + d3 * d3 + d4 * d4 + d5 * d5 + d6 * d6 + d7 * d7;
#pragma unroll
    for (int o = 8; o >= 1; o >>= 1) ss += __shfl_xor(ss, o, 64);
    float r = rsqrtf(ss * (1.f / DD) + 1e-5f);
    float4 gg0 = *(const float4*)(g1 + c);
    float4 gg1 = *(const float4*)(g1 + c + 4);
    float4 be0 = *(const float4*)(beta1 + c);
    float4 be1 = *(const float4*)(beta1 + c + 4);
    float o0 = d0 * r * gg0.x + be0.x;
    float o1 = d1 * r * gg0.y + be0.y;
    float o2 = d2 * r * gg0.z + be0.z;
    float o3 = d3 * r * gg0.w + be0.w;
    float o4 = d4 * r * gg1.x + be1.x;
    float o5 = d5 * r * gg1.y + be1.y;
    float o6 = d6 * r * gg1.z + be1.z;
    float o7 = d7 * r * gg1.w + be1.w;
    uint4 pk;
    pk.x = (unsigned)f2bf(o0) | ((unsigned)f2bf(o1) << 16);
    pk.y = (unsigned)f2bf(o2) | ((unsigned)f2bf(o3) << 16);
    pk.z = (unsigned)f2bf(o4) | ((unsigned)f2bf(o5) << 16);
    pk.w = (unsigned)f2bf(o6) | ((unsigned)f2bf(o7) << 16);
    *(uint4*)(x1b + (size_t)i * 64 + l * 4) = pk;
}

// ---- h2b = bf16( (x1 @ W2) * dis[row] )  via bf16 MFMA; one wave per 16-row strip ----
__global__ __launch_bounds__(256) void k_gemm_mfma(const unsigned short* __restrict__ x1b,
                                                   const unsigned short* __restrict__ Wb,
                                                   const float* __restrict__ dis,
                                                   unsigned short* __restrict__ hb, int N) {
    int wave = (blockIdx.x * blockDim.x + threadIdx.x) >> 6;
    int lane = threadIdx.x & 63;
    int row0 = wave * 16;
    if (row0 >= N) return;
    int m = lane & 15, quad = lane >> 4;

    short8 afr[4];
    const short8* ap = (const short8*)(x1b + (size_t)(row0 + m) * DD + quad * 8);
#pragma unroll
    for (int ks = 0; ks < 4; ks++) afr[ks] = ap[ks * 4];

    float4 dv = *(const float4*)(dis + row0 + quad * 4);
    float dr[4] = {dv.x, dv.y, dv.z, dv.w};

    const short8* bp = (const short8*)Wb + (size_t)lane;
#pragma unroll
    for (int nt = 0; nt < 8; nt++) {
        float4v acc = {0.f, 0.f, 0.f, 0.f};
#pragma unroll
        for (int ks = 0; ks < 4; ks++) {
            short8 bfr = bp[(nt * 4 + ks) * 64];
            acc = __builtin_amdgcn_mfma_f32_16x16x32_bf16(afr[ks], bfr, acc, 0, 0, 0);
        }
        int col = nt * 16 + m;
#pragma unroll
        for (int r = 0; r < 4; r++) {
            int row = row0 + quad * 4 + r;
            if (row < N) hb[(size_t)row * DD + col] = f2bf(acc[r] * dr[r]);
        }
    }
}

// ---- layer 2: 4 nodes/wave, lane-cooperative masked batches of 16 edges ----
__global__ __launch_bounds__(256) void k_node2(const int* __restrict__ rowptr,
                                               const unsigned* __restrict__ recs,
                                               const unsigned* __restrict__ x1b,
                                               const unsigned* __restrict__ h2b,
                                               const float* __restrict__ dis,
                                               const float* __restrict__ b2,
                                               const float* __restrict__ g2,
                                               const float* __restrict__ beta2,
                                               float* __restrict__ out, int N) {
    int gid = blockIdx.x * blockDim.x + threadIdx.x;
    int wave = gid >> 6;
    int lane = threadIdx.x & 63;
    int qtr = lane >> 4;
    int l = lane & 15;
    int qbase = lane & 48;
    int i = wave * 4 + qtr;
    if (i >= N) return;
    int r0 = rowptr[i], r1 = rowptr[i + 1];
    int c = l * 8;
    float a0 = 0.f, a1 = 0.f, a2 = 0.f, a3 = 0.f, a4 = 0.f, a5 = 0.f, a6 = 0.f, a7 = 0.f;
    for (int j0 = r0; j0 < r1; j0 += 16) {
        int pidx = j0 + l;
        unsigned rv = recs[(pidx < r1) ? pidx : (r1 - 1)];
        int lim = r1 - j0;
#pragma unroll
        for (int q = 0; q < 16; q++) {
            unsigned s = __shfl(rv, qbase + q, 64) & 0xFFFFu;
            float w = (q < lim) ? 1.f : 0.f;
            uint4 a = *(const uint4*)(h2b + (size_t)s * 64 + l * 4);
            a0 += bflo(a.x) * w; a1 += bfhi(a.x) * w;
            a2 += bflo(a.y) * w; a3 += bfhi(a.y) * w;
            a4 += bflo(a.z) * w; a5 += bfhi(a.z) * w;
            a6 += bflo(a.w) * w; a7 += bfhi(a.w) * w;
        }
    }
    float di = dis[i];
    uint4 xv = *(const uint4*)(x1b + (size_t)i * 64 + l * 4);
    uint4 hv = *(const uint4*)(h2b + (size_t)i * 64 + l * 4);   // already scaled by dis[i]
    float4 bb0 = *(const float4*)(b2 + c);
    float4 bb1 = *(const float4*)(b2 + c + 4);
    float v0 = bflo(xv.x) + di * (a0 + bflo(hv.x)) + bb0.x;
    float v1 = bfhi(xv.x) + di * (a1 + bfhi(hv.x)) + bb0.y;
    float v2 = bflo(xv.y) + di * (a2 + bflo(hv.y)) + bb0.z;
    float v3 = bfhi(xv.y) + di * (a3 + bfhi(hv.y)) + bb0.w;
    float v4 = bflo(xv.z) + di * (a4 + bflo(hv.z)) + bb1.x;
    float v5 = bfhi(xv.z) + di * (a5 + bfhi(hv.z)) + bb1.y;
    float v6 = bflo(xv.w) + di * (a6 + bflo(hv.w)) + bb1.z;
    float v7 = bfhi(xv.w) + di * (a7 + bfhi(hv.w)) + bb1.w;
    float sum = v0 + v1 + v2 + v3 + v4 + v5 + v6 + v7;
#pragma unroll
    for (int o = 8; o >= 1; o >>= 1) sum += __shfl_xor(sum, o, 64);
    float mu = sum * (1.f / DD);
    float d0 = v0 - mu, d1 = v1 - mu, d2 = v2 - mu, d3 = v3 - mu;
    float d4 = v4 - mu, d5 = v5 - mu, d6 = v6 - mu, d7 = v7 - mu;
    float ss = d0 * d0 + d1 * d1 + d2 * d2 + d3 * d3 + d4 * d4 + d5 * d5 + d6 * d6 + d7 * d7;
#pragma unroll
    for (int o = 8; o >= 1; o >>= 1) ss += __shfl_xor(ss, o, 64);
    float r = rsqrtf(ss * (1.f / DD) + 1e-5f);
    float4 gg0 = *(const float4*)(g2 + c);
    float4 gg1 = *(const float4*)(g2 + c + 4);
    float4 be0 = *(const float4*)(beta2 + c);
    float4 be1 = *(const float4*)(beta2 + c + 4);
    float4 o0, o1;
    o0.x = d0 * r * gg0.x + be0.x;
    o0.y = d1 * r * gg0.y + be0.y;
    o0.z = d2 * r * gg0.z + be0.z;
    o0.w = d3 * r * gg0.w + be0.w;
    o1.x = d4 * r * gg1.x + be1.x;
    o1.y = d5 * r * gg1.y + be1.y;
    o1.z = d6 * r * gg1.z + be1.z;
    o1.w = d7 * r * gg1.w + be1.w;
    *(float4*)(out + (size_t)i * DD + c) = o0;
    *(float4*)(out + (size_t)i * DD + c + 4) = o1;
}

extern "C" void kernel_launch(void* const* d_in, const int* in_sizes, int n_in,
                              void* d_out, int out_size, void* d_ws, size_t ws_size,
                              hipStream_t stream) {
    const int* node_ids = (const int*)d_in[0];
    const int* edge_index = (const int*)d_in[1];
    const float* emb   = (const float*)d_in[2];
    const float* W1    = (const float*)d_in[3];
    const float* b1    = (const float*)d_in[4];
    const float* W2    = (const float*)d_in[5];
    const float* b2    = (const float*)d_in[6];
    const float* g1    = (const float*)d_in[7];
    const float* beta1 = (const float*)d_in[8];
    const float* g2    = (const float*)d_in[9];
    const float* beta2 = (const float*)d_in[10];
    const int N = in_sizes[0];
    const int E = in_sizes[1] / 2;
    const int* srcp = edge_index;
    const int* dstp = edge_index + E;
    float* out = (float*)d_out;

    char* base = (char*)d_ws;
    size_t off = 0;
    auto carve = [&](size_t bytes) -> void* {
        void* p = base + off;
        off += (bytes + 255) & ~(size_t)255;
        return p;
    };
    int*      cnt    = (int*)carve((size_t)N * 4);
    int*      rowptr = (int*)carve((size_t)(N + 1) * 4);
    int*      cursor = (int*)carve((size_t)N * 4);
    float*    dis    = (float*)carve((size_t)(N + 16) * 4);
    int*      bsum   = (int*)carve((size_t)256 * 4);
    unsigned* recs   = (unsigned*)carve((size_t)E * 4);
    unsigned* embW1b = (unsigned*)carve((size_t)512 * 64 * 4);
    unsigned* x1b    = (unsigned*)carve((size_t)(N + 16) * 64 * 4);
    unsigned* h2b    = (unsigned*)carve((size_t)(N + 16) * 64 * 4);
    unsigned short* Wb = (unsigned short*)carve((size_t)DD * DD * 2);
    (void)ws_size; (void)n_in; (void)out_size;

    const int TB = 256;
    const int B = (N + 1023) / 1024;   // 49 scan tiles

    k_init<<<136 + B, TB, 0, stream>>>(emb, W1, W2, embW1b, Wb, cnt, N);
    k_hist<<<(E + TB - 1) / TB, TB, 0, stream>>>(dstp, cnt, E);
    k_scan1<<<B, 256, 0, stream>>>(cnt, rowptr, dis, bsum, N);
    k_scan23<<<(N + TB - 1) / TB, TB, 0, stream>>>(rowptr, cursor, bsum, B, N, E);
    k_bucket<<<(E + TB - 1) / TB, TB, 0, stream>>>(srcp, dstp, node_ids, cnt, cursor, recs, E);

    long long tn = (long long)((N + 3) / 4) * 64;   // one wave per 4 nodes
    int nodeBlocks = (int)((tn + TB - 1) / TB);
    k_node1<<<nodeBlocks, TB, 0, stream>>>(rowptr, recs, node_ids, emb, embW1b, dis,
                                           b1, g1, beta1, x1b, N);
    int waves = (N + 15) / 16;
    int gb = (waves + 3) / 4;
    k_gemm_mfma<<<gb, 256, 0, stream>>>((const unsigned short*)x1b, Wb, dis,
                                        (unsigned short*)h2b, N);
    k_node2<<<nodeBlocks, TB, 0, stream>>>(rowptr, recs, x1b, h2b, dis,
                                           b2, g2, beta2, out, N);
}